// Round 11
// baseline (266.631 us; speedup 1.0000x reference)
//
#include <hip/hip_runtime.h>

// VecInt: scaling-and-squaring integration, vel [2,128,128,128,3] fp32.
// v = vel/2^7; 7x: v = v + warp(v, v)  (border-clipped trilinear).
//
// Round-16: PASS-COUNT reduction (fuse 2 integration steps per launch).
// Ledger: latency (r14 asm single-epoch: flat), tier (r7 L2: flat),
// occupancy/waves (r11: flat), MLP (r8-r10: flat), transactions (r15
// LDS tiles: flat). Five structurally unrelated mid implementations all
// cost ~34-36us => the cost is PER-PASS (cross-XCD producer->consumer
// turnaround + ramp/drain), not per-instruction. Only lever left: fewer
// passes. 7 -> 5 launches:
//   first | fuse2(steps2,3) | fuse2(steps4,5) | tile<2>(step6) | last
// Halo math (exact): |u_k| <= 2^k*max|vel|/128, max|vel|<8 => steps 2-5
// displacement < 1 => 1 voxel halo per step => H=2 for a 2-step fusion.
// S=20^3 fp16x4 = 64.0KB static LDS. u_{k+1} computed on 18^3 interior
// into registers (static-indexed, rule #20), synced, written in place,
// then u_{k+2} on the 16^3 tile. fp16 rounding points identical to the
// global round-trip => absmax unchanged.

#define NVOX_PER_B (1 << 21)          // 128^3
#define NXCD 8

typedef _Float16 h16;
typedef __attribute__((ext_vector_type(4))) _Float16 h16x4;   // 8 bytes
typedef __attribute__((ext_vector_type(8))) _Float16 h16x8;   // 16 bytes
typedef __attribute__((ext_vector_type(4))) float    f32x4;   // 16 bytes

__device__ __forceinline__ int swz_idx()
{
    // chunked XCD swizzle: contiguous 1/8 of the grid per XCD (grid%8==0)
    int nb = gridDim.x;
    int chunk = nb >> 3;
    int bid = blockIdx.x;
    int newbid = (bid & (NXCD - 1)) * chunk + (bid >> 3);
    return newbid * blockDim.x + threadIdx.x;
}

// ---- full 8-corner setup (f32 first pass) ------------------------------
__device__ __forceinline__ void tri_setup(
    int x, int y, int z, float fx, float fy, float fz,
    int* off, float* w)
{
    float lx = fminf(fmaxf((float)x + fx, 0.0f), 127.0f);
    float ly = fminf(fmaxf((float)y + fy, 0.0f), 127.0f);
    float lz = fminf(fmaxf((float)z + fz, 0.0f), 127.0f);

    float flx = floorf(lx), fly = floorf(ly), flz = floorf(lz);
    float wx1 = lx - flx, wy1 = ly - fly, wz1 = lz - flz;
    float wx0 = 1.0f - wx1, wy0 = 1.0f - wy1, wz0 = 1.0f - wz1;

    int x0 = (int)flx, y0 = (int)fly, z0 = (int)flz;
    int x1 = min(x0 + 1, 127);
    int y1 = min(y0 + 1, 127);
    int z1 = min(z0 + 1, 127);

    off[0] = (x0 << 14) + (y0 << 7) + z0;
    off[1] = (x0 << 14) + (y0 << 7) + z1;
    off[2] = (x0 << 14) + (y1 << 7) + z0;
    off[3] = (x0 << 14) + (y1 << 7) + z1;
    off[4] = (x1 << 14) + (y0 << 7) + z0;
    off[5] = (x1 << 14) + (y0 << 7) + z1;
    off[6] = (x1 << 14) + (y1 << 7) + z0;
    off[7] = (x1 << 14) + (y1 << 7) + z1;
    w[0] = wx0 * wy0 * wz0;  w[1] = wx0 * wy0 * wz1;
    w[2] = wx0 * wy1 * wz0;  w[3] = wx0 * wy1 * wz1;
    w[4] = wx1 * wy0 * wz0;  w[5] = wx1 * wy0 * wz1;
    w[6] = wx1 * wy1 * wz0;  w[7] = wx1 * wy1 * wz1;
}

// ---- pair setup (fp16 global last pass) --------------------------------
__device__ __forceinline__ void tri_setup_pair(
    int x, int y, int z, float fx, float fy, float fz,
    int* offp, float* wxy, float& wz0, float& wz1)
{
    float lx = fminf(fmaxf((float)x + fx, 0.0f), 127.0f);
    float ly = fminf(fmaxf((float)y + fy, 0.0f), 127.0f);
    float lz = fminf(fmaxf((float)z + fz, 0.0f), 127.0f);

    float flx = floorf(lx), fly = floorf(ly), flz = floorf(lz);
    float wx1 = lx - flx, wy1 = ly - fly;
    wz1 = lz - flz;                      // == 0 exactly when z0 == 127
    float wx0 = 1.0f - wx1, wy0 = 1.0f - wy1;
    wz0 = 1.0f - wz1;

    int x0 = (int)flx, y0 = (int)fly, z0 = (int)flz;
    int x1 = min(x0 + 1, 127);
    int y1 = min(y0 + 1, 127);

    offp[0] = (x0 << 14) + (y0 << 7) + z0;
    offp[1] = (x0 << 14) + (y1 << 7) + z0;
    offp[2] = (x1 << 14) + (y0 << 7) + z0;
    offp[3] = (x1 << 14) + (y1 << 7) + z0;
    wxy[0] = wx0 * wy0;  wxy[1] = wx0 * wy1;
    wxy[2] = wx1 * wy0;  wxy[3] = wx1 * wy1;
}

__device__ __forceinline__ void sample_pairs(
    const h16x4* __restrict__ vb, const int* offp, const float* wxy,
    float wz0, float wz1, float& ox, float& oy, float& oz)
{
    f32x4 q0 = *(const f32x4*)(vb + offp[0]);
    f32x4 q1 = *(const f32x4*)(vb + offp[1]);
    f32x4 q2 = *(const f32x4*)(vb + offp[2]);
    f32x4 q3 = *(const f32x4*)(vb + offp[3]);

    h16x8 c0 = __builtin_bit_cast(h16x8, q0);
    h16x8 c1 = __builtin_bit_cast(h16x8, q1);
    h16x8 c2 = __builtin_bit_cast(h16x8, q2);
    h16x8 c3 = __builtin_bit_cast(h16x8, q3);

    float sx0 = wz0 * (float)c0[0] + wz1 * (float)c0[4];
    float sy0 = wz0 * (float)c0[1] + wz1 * (float)c0[5];
    float sz0 = wz0 * (float)c0[2] + wz1 * (float)c0[6];
    float sx1 = wz0 * (float)c1[0] + wz1 * (float)c1[4];
    float sy1 = wz0 * (float)c1[1] + wz1 * (float)c1[5];
    float sz1 = wz0 * (float)c1[2] + wz1 * (float)c1[6];
    float sx2 = wz0 * (float)c2[0] + wz1 * (float)c2[4];
    float sy2 = wz0 * (float)c2[1] + wz1 * (float)c2[5];
    float sz2 = wz0 * (float)c2[2] + wz1 * (float)c2[6];
    float sx3 = wz0 * (float)c3[0] + wz1 * (float)c3[4];
    float sy3 = wz0 * (float)c3[1] + wz1 * (float)c3[5];
    float sz3 = wz0 * (float)c3[2] + wz1 * (float)c3[6];

    ox = wxy[0] * sx0 + wxy[1] * sx1 + wxy[2] * sx2 + wxy[3] * sx3;
    oy = wxy[0] * sy0 + wxy[1] * sy1 + wxy[2] * sy2 + wxy[3] * sy3;
    oz = wxy[0] * sz0 + wxy[1] * sz1 + wxy[2] * sz2 + wxy[3] * sz3;
}

// ---- LDS sampler shared by tiled kernels (r15 math order) --------------
// Samples st (span SS, halo HH) at (gx,gy,gz)+f, border-clipped. All
// corner staged coords provably within [0,SS-1] for |f|<HH-ish bounds
// established per call site.
template<int SS, int HH>
__device__ __forceinline__ void sample_lds(
    const h16x4* st, int gx, int gy, int gz,
    int ox, int oy, int oz,
    float fx, float fy, float fz,
    float& oxv, float& oyv, float& ozv)
{
    float cx = fminf(fmaxf((float)gx + fx, 0.0f), 127.0f);
    float cy = fminf(fmaxf((float)gy + fy, 0.0f), 127.0f);
    float cz = fminf(fmaxf((float)gz + fz, 0.0f), 127.0f);

    float flx = floorf(cx), fly = floorf(cy), flz = floorf(cz);
    float wx1 = cx - flx, wy1 = cy - fly, wz1 = cz - flz;
    float wx0 = 1.0f - wx1, wy0 = 1.0f - wy1, wz0 = 1.0f - wz1;

    int x0 = (int)flx, y0 = (int)fly, z0 = (int)flz;
    int x1 = min(x0 + 1, 127);
    int y1 = min(y0 + 1, 127);
    int z1 = min(z0 + 1, 127);

    int X0 = x0 - ox + HH, X1 = x1 - ox + HH;
    int Y0 = y0 - oy + HH, Y1 = y1 - oy + HH;
    int Z0 = z0 - oz + HH, Z1 = z1 - oz + HH;

    h16x4 c00l = st[(X0 * SS + Y0) * SS + Z0];
    h16x4 c00h = st[(X0 * SS + Y0) * SS + Z1];
    h16x4 c01l = st[(X0 * SS + Y1) * SS + Z0];
    h16x4 c01h = st[(X0 * SS + Y1) * SS + Z1];
    h16x4 c10l = st[(X1 * SS + Y0) * SS + Z0];
    h16x4 c10h = st[(X1 * SS + Y0) * SS + Z1];
    h16x4 c11l = st[(X1 * SS + Y1) * SS + Z0];
    h16x4 c11h = st[(X1 * SS + Y1) * SS + Z1];

    float w00 = wx0 * wy0, w01 = wx0 * wy1;
    float w10 = wx1 * wy0, w11 = wx1 * wy1;

    float sx0 = wz0 * (float)c00l.x + wz1 * (float)c00h.x;
    float sy0 = wz0 * (float)c00l.y + wz1 * (float)c00h.y;
    float sz0 = wz0 * (float)c00l.z + wz1 * (float)c00h.z;
    float sx1 = wz0 * (float)c01l.x + wz1 * (float)c01h.x;
    float sy1 = wz0 * (float)c01l.y + wz1 * (float)c01h.y;
    float sz1 = wz0 * (float)c01l.z + wz1 * (float)c01h.z;
    float sx2 = wz0 * (float)c10l.x + wz1 * (float)c10h.x;
    float sy2 = wz0 * (float)c10l.y + wz1 * (float)c10h.y;
    float sz2 = wz0 * (float)c10l.z + wz1 * (float)c10h.z;
    float sx3 = wz0 * (float)c11l.x + wz1 * (float)c11h.x;
    float sy3 = wz0 * (float)c11l.y + wz1 * (float)c11h.y;
    float sz3 = wz0 * (float)c11l.z + wz1 * (float)c11h.z;

    oxv = w00 * sx0 + w01 * sx1 + w10 * sx2 + w11 * sx3;
    oyv = w00 * sy0 + w01 * sy1 + w10 * sy2 + w11 * sy3;
    ozv = w00 * sz0 + w01 * sz1 + w10 * sz2 + w11 * sz3;
}

// ---- fused 2-step tile kernel: T=16, H=2, S=20 (64.0KB LDS) ------------
// Requires BOTH fused steps to have displacement < 1 (steps 2-5: proven).
// Phase0: stage u_k on 20^3 (clamped, each voxel once).
// Phase1: u_{k+1} on interior 18^3 -> registers (static-indexed).
// Phase2: write back in place; Phase3: u_{k+2} on 16^3 tile -> global.
__global__ __launch_bounds__(512) void vecint_fuse2(
    const h16x4* __restrict__ vin, h16x4* __restrict__ vout)
{
    constexpr int S = 20;
    constexpr int NS = S * S * S;        // 8000 voxels, 64000 B
    __shared__ h16x4 st[NS];

    // chunked XCD swizzle on tile id (1024 tiles, %8==0)
    int nb = gridDim.x;
    int chunk = nb >> 3;
    int nbid = (blockIdx.x & (NXCD - 1)) * chunk + (blockIdx.x >> 3);

    int tz = nbid & 7, ty = (nbid >> 3) & 7, tx = (nbid >> 6) & 7;
    int b = nbid >> 9;
    int ox = tx * 16, oy = ty * 16, oz = tz * 16;

    const h16x4* vb = vin + ((size_t)b << 21);
    h16x4* ob = vout + ((size_t)b << 21);

    int t = threadIdx.x;

    // ---- phase 0: stage (each staged voxel read once, clamped) ---------
    for (int s = t; s < NS; s += 512) {
        int si = s / (S * S);
        int r  = s - si * (S * S);
        int sj = r / S;
        int sk = r - sj * S;
        int gx = min(max(ox - 2 + si, 0), 127);
        int gy = min(max(oy - 2 + sj, 0), 127);
        int gz = min(max(oz - 2 + sk, 0), 127);
        st[s] = vb[(gx << 14) + (gy << 7) + gz];
    }
    __syncthreads();

    // ---- phase 1: u_{k+1} on interior 18^3 (staged coords 1..18) -------
    constexpr int NI = 18 * 18 * 18;     // 5832
    float rx[12], ry[12], rz[12];
#pragma unroll
    for (int it = 0; it < 12; ++it) {
        int p = t + it * 512;
        if (p < NI) {
            int si = p / 324;            // 18*18
            int r2 = p - si * 324;
            int sj = r2 / 18;
            int sk = r2 - sj * 18;
            int X = si + 1, Y = sj + 1, Z = sk + 1;
            int gx = ox - 2 + X, gy = oy - 2 + Y, gz = oz - 2 + Z;

            h16x4 f = st[(X * S + Y) * S + Z];
            float fx = (float)f.x, fy = (float)f.y, fz = (float)f.z;
            float oxv, oyv, ozv;
            sample_lds<S, 2>(st, gx, gy, gz, ox, oy, oz,
                             fx, fy, fz, oxv, oyv, ozv);
            rx[it] = fx + oxv;
            ry[it] = fy + oyv;
            rz[it] = fz + ozv;
        }
    }
    __syncthreads();

    // ---- phase 2: write u_{k+1} back in place (fp16, same rounding as
    // the global round-trip had) -----------------------------------------
#pragma unroll
    for (int it = 0; it < 12; ++it) {
        int p = t + it * 512;
        if (p < NI) {
            int si = p / 324;
            int r2 = p - si * 324;
            int sj = r2 / 18;
            int sk = r2 - sj * 18;
            h16x4 o;
            o.x = (h16)rx[it];
            o.y = (h16)ry[it];
            o.z = (h16)rz[it];
            o.w = (h16)0.0f;
            st[((si + 1) * S + (sj + 1)) * S + (sk + 1)] = o;
        }
    }
    __syncthreads();

    // ---- phase 3: u_{k+2} on the 16^3 tile -> global -------------------
    int lz = t & 15;
    int ly = (t >> 4) & 15;
    int lx8 = (t >> 8);                  // 0..1
    int z = oz + lz, y = oy + ly;

#pragma unroll
    for (int i = 0; i < 8; ++i) {
        int lx = lx8 * 8 + i;
        int x = ox + lx;

        h16x4 f = st[((lx + 2) * S + (ly + 2)) * S + (lz + 2)];
        float fx = (float)f.x, fy = (float)f.y, fz = (float)f.z;
        float oxv, oyv, ozv;
        sample_lds<S, 2>(st, x, y, z, ox, oy, oz,
                         fx, fy, fz, oxv, oyv, ozv);

        h16x4 o;
        o.x = (h16)(fx + oxv);
        o.y = (h16)(fy + oyv);
        o.z = (h16)(fz + ozv);
        o.w = (h16)0.0f;
        ob[(x << 14) + (y << 7) + z] = o;
    }
}

// ---- single-step tile kernel (step 6, disp<2): r15's proven tile<2> ----
__global__ __launch_bounds__(512) void vecint_tile2(
    const h16x4* __restrict__ vin, h16x4* __restrict__ vout)
{
    constexpr int S = 20;
    constexpr int NS = S * S * S;
    __shared__ h16x4 st[NS];

    int nb = gridDim.x;
    int chunk = nb >> 3;
    int nbid = (blockIdx.x & (NXCD - 1)) * chunk + (blockIdx.x >> 3);

    int tz = nbid & 7, ty = (nbid >> 3) & 7, tx = (nbid >> 6) & 7;
    int b = nbid >> 9;
    int ox = tx * 16, oy = ty * 16, oz = tz * 16;

    const h16x4* vb = vin + ((size_t)b << 21);
    h16x4* ob = vout + ((size_t)b << 21);

    int t = threadIdx.x;

    for (int s = t; s < NS; s += 512) {
        int si = s / (S * S);
        int r  = s - si * (S * S);
        int sj = r / S;
        int sk = r - sj * S;
        int gx = min(max(ox - 2 + si, 0), 127);
        int gy = min(max(oy - 2 + sj, 0), 127);
        int gz = min(max(oz - 2 + sk, 0), 127);
        st[s] = vb[(gx << 14) + (gy << 7) + gz];
    }
    __syncthreads();

    int lz = t & 15;
    int ly = (t >> 4) & 15;
    int lx8 = (t >> 8);
    int z = oz + lz, y = oy + ly;

#pragma unroll
    for (int i = 0; i < 8; ++i) {
        int lx = lx8 * 8 + i;
        int x = ox + lx;

        h16x4 f = st[((lx + 2) * S + (ly + 2)) * S + (lz + 2)];
        float fx = (float)f.x, fy = (float)f.y, fz = (float)f.z;
        float oxv, oyv, ozv;
        sample_lds<S, 2>(st, x, y, z, ox, oy, oz,
                         fx, fy, fz, oxv, oyv, ozv);

        h16x4 o;
        o.x = (h16)(fx + oxv);
        o.y = (h16)(fy + oyv);
        o.z = (h16)(fz + ozv);
        o.w = (h16)0.0f;
        ob[(x << 14) + (y << 7) + z] = o;
    }
}

// ---- step 1: f32 packed vel -> fp16x4 field (fuses the /128 scale) -----
__global__ __launch_bounds__(256, 6) void vecint_first(
    const float* __restrict__ vin, h16x4* __restrict__ vout,
    float scale, int nvox)
{
    int idx = swz_idx();
    if (idx >= nvox) return;

    int z = idx & 127;
    int y = (idx >> 7) & 127;
    int x = (idx >> 14) & 127;
    int b = idx >> 21;

    int base = idx * 3;
    float fx = vin[base + 0] * scale;
    float fy = vin[base + 1] * scale;
    float fz = vin[base + 2] * scale;

    int off[8]; float w[8];
    tri_setup(x, y, z, fx, fy, fz, off, w);

    const float* vb = vin + (size_t)b * (NVOX_PER_B * 3);

    float ox = 0.0f, oy = 0.0f, oz = 0.0f;
#pragma unroll
    for (int i = 0; i < 8; ++i) {
        const float* p = vb + (size_t)off[i] * 3;
        ox += w[i] * p[0]; oy += w[i] * p[1]; oz += w[i] * p[2];
    }

    h16x4 o;
    o.x = (h16)(fx + scale * ox);
    o.y = (h16)(fy + scale * oy);
    o.z = (h16)(fz + scale * oz);
    o.w = (h16)0.0f;
    vout[idx] = o;
}

// ---- step 7: fp16x4 -> f32 packed (global; disp<4 too big for LDS) -----
__global__ __launch_bounds__(256, 6) void vecint_last(
    const h16x4* __restrict__ vin, float* __restrict__ vout, int nvox)
{
    int idx = swz_idx();
    if (idx >= nvox) return;

    int z = idx & 127;
    int y = (idx >> 7) & 127;
    int x = (idx >> 14) & 127;
    int b = idx >> 21;

    h16x4 f = vin[idx];
    float fx = (float)f.x, fy = (float)f.y, fz = (float)f.z;

    int offp[4]; float wxy[4], wz0, wz1;
    tri_setup_pair(x, y, z, fx, fy, fz, offp, wxy, wz0, wz1);

    const h16x4* vb = vin + ((size_t)b << 21);
    float ox, oy, oz;
    sample_pairs(vb, offp, wxy, wz0, wz1, ox, oy, oz);

    int base = idx * 3;
    vout[base + 0] = fx + ox;
    vout[base + 1] = fy + oy;
    vout[base + 2] = fz + oz;
}

extern "C" void kernel_launch(void* const* d_in, const int* in_sizes, int n_in,
                              void* d_out, int out_size, void* d_ws, size_t ws_size,
                              hipStream_t stream) {
    const float* vel = (const float*)d_in[0];
    float* out = (float*)d_out;

    int nvox = in_sizes[0] / 3;            // 4,194,304 voxels (2 batches)
    int blocks = (nvox + 255) / 256;       // 16384 (divisible by 8)
    int tblocks = 1024;                    // 8x8x8 tiles x 2 batches (%8==0)
    float s0 = 1.0f / 128.0f;              // 1 / 2^INT_STEPS

    // D = fp16 field living in the first 33.5 MB of d_out (d_out is 50.3 MB);
    // W = fp16 field in d_ws.
    h16x4* D = (h16x4*)d_out;
    h16x4* W = (h16x4*)d_ws;

    // zero 16B past each field: pass-7's z-pair load hi half (weight 0)
    hipMemsetAsync((char*)d_out + (size_t)nvox * 8, 0, 16, stream);
    hipMemsetAsync((char*)d_ws  + (size_t)nvox * 8, 0, 16, stream);

    vecint_first<<<blocks,  256, 0, stream>>>(vel, D, s0, nvox);  // step 1
    vecint_fuse2<<<tblocks, 512, 0, stream>>>(D, W);              // steps 2,3
    vecint_fuse2<<<tblocks, 512, 0, stream>>>(W, D);              // steps 4,5
    vecint_tile2<<<tblocks, 512, 0, stream>>>(D, W);              // step 6
    vecint_last <<<blocks,  256, 0, stream>>>(W, out, nvox);      // step 7
}

// Round 12
// 248.622 us; speedup vs baseline: 1.0724x; 1.0724x over previous
//
#include <hip/hip_runtime.h>

// VecInt: scaling-and-squaring integration, vel [2,128,128,128,3] fp32.
// v = vel/2^7; 7x: v = v + warp(v, v)  (border-clipped trilinear).
//
// Round-17: extend fusion front + sampler v2.
// r16 finding: fused tile kernel = 26us/step (vs 34 single-step pass) with
// VALUBusy 69% + 4.7M LDS bank-conflict cycles => inside fused kernels the
// cost is VALU + conflicts (attackable), unlike the global-pass floor.
// Changes:
//  1. first2: steps 1+2 tiled+fused; stages v0=vel/128 (f32->fp16, dense)
//     -- removes the 50us 24-gather f32 pass entirely.
//  2. sampler v2: block-uniform local clamp bounds (no global<->local
//     conversions) + z-pair reads (Z0,Z0+1 always in-range; wz1==0 exactly
//     when clamped) -> 8 LDS reads become 4 ds_read2_b64.
//  3. X-plane pad: lidx = X*(S*S+1)+Y*S+Z (X-stride was = 0 mod 32 banks).
// Structure: first2(1,2) | fuse2b(3,4) | tile1(5) | tile2b(6) | last(7).
// Halo math (exact, |u_k| <= 2^k*max|vel|/128, max|vel|<8):
//   step1 in first2: disp<1/16; step2: <1/8 (H=2 covers both).
//   steps 3,4: <1 (H=2). step5: <1 (H=1). step6: <2 (H=2). step7: <4 (global).

#define NVOX_PER_B (1 << 21)          // 128^3
#define NXCD 8

typedef _Float16 h16;
typedef __attribute__((ext_vector_type(4))) _Float16 h16x4;   // 8 bytes
typedef __attribute__((ext_vector_type(8))) _Float16 h16x8;   // 16 bytes
typedef __attribute__((ext_vector_type(4))) float    f32x4;   // 16 bytes

__device__ __forceinline__ int swz_idx()
{
    int nb = gridDim.x;
    int chunk = nb >> 3;
    int bid = blockIdx.x;
    int newbid = (bid & (NXCD - 1)) * chunk + (bid >> 3);
    return newbid * blockDim.x + threadIdx.x;
}

// ---- sampler v2: local coords, block-uniform bounds, z-pair reads ------
// st layout: lidx(X,Y,Z) = X*(S*S+1) + Y*S + Z  (X-plane padded +1 elem).
// Math order identical to r15/r16 sampler (absmax-stable).
template<int S>
__device__ __forceinline__ void sample_v2(
    const h16x4* st,
    float bx, float by, float bz,          // local integer base as float
    float fx, float fy, float fz,
    float clox, float cloy, float cloz,    // block-uniform clamp lo (local)
    float chix, float chiy, float chiz,    // block-uniform clamp hi (local)
    int ihix, int ihiy,                    // block-uniform +1 corner cap
    float& oxv, float& oyv, float& ozv)
{
    float cx = fminf(fmaxf(bx + fx, clox), chix);
    float cy = fminf(fmaxf(by + fy, cloy), chiy);
    float cz = fminf(fmaxf(bz + fz, cloz), chiz);

    float flx = floorf(cx), fly = floorf(cy), flz = floorf(cz);
    float wx1 = cx - flx, wy1 = cy - fly, wz1 = cz - flz;
    float wx0 = 1.0f - wx1, wy0 = 1.0f - wy1, wz0 = 1.0f - wz1;

    int X0 = (int)flx, Y0 = (int)fly, Z0 = (int)flz;
    int X1 = min(X0 + 1, ihix);
    int Y1 = min(Y0 + 1, ihiy);
    // Z pair: Z0+1 is always a valid staged slot; when the clamp bound
    // binds, wz1 == 0 exactly and the hi value (finite) is weight-free.

    int r00 = X0 * (S * S + 1) + Y0 * S + Z0;
    int r01 = X0 * (S * S + 1) + Y1 * S + Z0;
    int r10 = X1 * (S * S + 1) + Y0 * S + Z0;
    int r11 = X1 * (S * S + 1) + Y1 * S + Z0;

    h16x4 a0 = st[r00], a1 = st[r00 + 1];
    h16x4 b0 = st[r01], b1 = st[r01 + 1];
    h16x4 c0 = st[r10], c1 = st[r10 + 1];
    h16x4 d0 = st[r11], d1 = st[r11 + 1];

    float w00 = wx0 * wy0, w01 = wx0 * wy1;
    float w10 = wx1 * wy0, w11 = wx1 * wy1;

    float sx0 = wz0 * (float)a0.x + wz1 * (float)a1.x;
    float sy0 = wz0 * (float)a0.y + wz1 * (float)a1.y;
    float sz0 = wz0 * (float)a0.z + wz1 * (float)a1.z;
    float sx1 = wz0 * (float)b0.x + wz1 * (float)b1.x;
    float sy1 = wz0 * (float)b0.y + wz1 * (float)b1.y;
    float sz1 = wz0 * (float)b0.z + wz1 * (float)b1.z;
    float sx2 = wz0 * (float)c0.x + wz1 * (float)c1.x;
    float sy2 = wz0 * (float)c0.y + wz1 * (float)c1.y;
    float sz2 = wz0 * (float)c0.z + wz1 * (float)c1.z;
    float sx3 = wz0 * (float)d0.x + wz1 * (float)d1.x;
    float sy3 = wz0 * (float)d0.y + wz1 * (float)d1.y;
    float sz3 = wz0 * (float)d0.z + wz1 * (float)d1.z;

    oxv = w00 * sx0 + w01 * sx1 + w10 * sx2 + w11 * sx3;
    oyv = w00 * sy0 + w01 * sy1 + w10 * sy2 + w11 * sy3;
    ozv = w00 * sz0 + w01 * sz1 + w10 * sz2 + w11 * sz3;
}

// ---- tile-id decode + bounds (shared by all tiled kernels) -------------
struct TileInfo {
    int ox, oy, oz, b;
    float clox, cloy, cloz, chix, chiy, chiz;
    int ihix, ihiy;
};

template<int H>
__device__ __forceinline__ TileInfo tile_info()
{
    int nb = gridDim.x;
    int chunk = nb >> 3;
    int nbid = (blockIdx.x & (NXCD - 1)) * chunk + (blockIdx.x >> 3);
    TileInfo ti;
    int tz = nbid & 7, ty = (nbid >> 3) & 7, tx = (nbid >> 6) & 7;
    ti.b = nbid >> 9;
    ti.ox = tx * 16; ti.oy = ty * 16; ti.oz = tz * 16;
    ti.clox = (float)(H - ti.ox);
    ti.cloy = (float)(H - ti.oy);
    ti.cloz = (float)(H - ti.oz);
    ti.chix = (float)(127 - ti.ox + H);
    ti.chiy = (float)(127 - ti.oy + H);
    ti.chiz = (float)(127 - ti.oz + H);
    ti.ihix = 127 - ti.ox + H;
    ti.ihiy = 127 - ti.oy + H;
    return ti;
}

// ---- steps 1+2 fused: stage v0=vel*s from f32, two warps, out fp16 -----
__global__ __launch_bounds__(512) void vecint_first2(
    const float* __restrict__ vin, h16x4* __restrict__ vout, float scale)
{
    constexpr int S = 20, H = 2;
    __shared__ h16x4 st[S * (S * S + 1)];    // 64,160 B

    TileInfo ti = tile_info<H>();
    const float* vb = vin + (size_t)ti.b * (NVOX_PER_B * 3);
    h16x4* ob = vout + ((size_t)ti.b << 21);
    int t = threadIdx.x;

    // stage: v0 = vel*scale -> fp16 (each staged voxel read once, clamped)
    for (int s = t; s < S * S * S; s += 512) {
        int si = s / (S * S);
        int r  = s - si * (S * S);
        int sj = r / S;
        int sk = r - sj * S;
        int gx = min(max(ti.ox - H + si, 0), 127);
        int gy = min(max(ti.oy - H + sj, 0), 127);
        int gz = min(max(ti.oz - H + sk, 0), 127);
        const float* p = vb + (size_t)((gx << 14) + (gy << 7) + gz) * 3;
        h16x4 v;
        v.x = (h16)(p[0] * scale);
        v.y = (h16)(p[1] * scale);
        v.z = (h16)(p[2] * scale);
        v.w = (h16)0.0f;
        st[si * (S * S + 1) + sj * S + sk] = v;
    }
    __syncthreads();

    // step 1 on interior 18^3 -> registers
    constexpr int NI = 18 * 18 * 18;
    float rx[12], ry[12], rz[12];
#pragma unroll
    for (int it = 0; it < 12; ++it) {
        int p = t + it * 512;
        if (p < NI) {
            int si = p / 324;
            int r2 = p - si * 324;
            int sj = r2 / 18;
            int sk = r2 - sj * 18;
            int X = si + 1, Y = sj + 1, Z = sk + 1;
            h16x4 f = st[X * (S * S + 1) + Y * S + Z];
            float fx = (float)f.x, fy = (float)f.y, fz = (float)f.z;
            float oxv, oyv, ozv;
            sample_v2<S>(st, (float)X, (float)Y, (float)Z, fx, fy, fz,
                         ti.clox, ti.cloy, ti.cloz, ti.chix, ti.chiy, ti.chiz,
                         ti.ihix, ti.ihiy, oxv, oyv, ozv);
            rx[it] = fx + oxv; ry[it] = fy + oyv; rz[it] = fz + ozv;
        }
    }
    __syncthreads();

    // write u1 back in place (fp16 rounding = global round-trip rounding)
#pragma unroll
    for (int it = 0; it < 12; ++it) {
        int p = t + it * 512;
        if (p < NI) {
            int si = p / 324;
            int r2 = p - si * 324;
            int sj = r2 / 18;
            int sk = r2 - sj * 18;
            h16x4 o;
            o.x = (h16)rx[it]; o.y = (h16)ry[it]; o.z = (h16)rz[it];
            o.w = (h16)0.0f;
            st[(si + 1) * (S * S + 1) + (sj + 1) * S + (sk + 1)] = o;
        }
    }
    __syncthreads();

    // step 2 on 16^3 tile -> global
    int lz = t & 15, ly = (t >> 4) & 15, lx8 = t >> 8;
#pragma unroll
    for (int i = 0; i < 8; ++i) {
        int lx = lx8 * 8 + i;
        int X = lx + H, Y = ly + H, Z = lz + H;
        h16x4 f = st[X * (S * S + 1) + Y * S + Z];
        float fx = (float)f.x, fy = (float)f.y, fz = (float)f.z;
        float oxv, oyv, ozv;
        sample_v2<S>(st, (float)X, (float)Y, (float)Z, fx, fy, fz,
                     ti.clox, ti.cloy, ti.cloz, ti.chix, ti.chiy, ti.chiz,
                     ti.ihix, ti.ihiy, oxv, oyv, ozv);
        h16x4 o;
        o.x = (h16)(fx + oxv); o.y = (h16)(fy + oyv); o.z = (h16)(fz + ozv);
        o.w = (h16)0.0f;
        ob[((ti.ox + lx) << 14) + ((ti.oy + ly) << 7) + (ti.oz + lz)] = o;
    }
}

// ---- steps 3+4 fused (fp16 field in/out), sampler v2 -------------------
__global__ __launch_bounds__(512) void vecint_fuse2b(
    const h16x4* __restrict__ vin, h16x4* __restrict__ vout)
{
    constexpr int S = 20, H = 2;
    __shared__ h16x4 st[S * (S * S + 1)];

    TileInfo ti = tile_info<H>();
    const h16x4* vb = vin + ((size_t)ti.b << 21);
    h16x4* ob = vout + ((size_t)ti.b << 21);
    int t = threadIdx.x;

    for (int s = t; s < S * S * S; s += 512) {
        int si = s / (S * S);
        int r  = s - si * (S * S);
        int sj = r / S;
        int sk = r - sj * S;
        int gx = min(max(ti.ox - H + si, 0), 127);
        int gy = min(max(ti.oy - H + sj, 0), 127);
        int gz = min(max(ti.oz - H + sk, 0), 127);
        st[si * (S * S + 1) + sj * S + sk] = vb[(gx << 14) + (gy << 7) + gz];
    }
    __syncthreads();

    constexpr int NI = 18 * 18 * 18;
    float rx[12], ry[12], rz[12];
#pragma unroll
    for (int it = 0; it < 12; ++it) {
        int p = t + it * 512;
        if (p < NI) {
            int si = p / 324;
            int r2 = p - si * 324;
            int sj = r2 / 18;
            int sk = r2 - sj * 18;
            int X = si + 1, Y = sj + 1, Z = sk + 1;
            h16x4 f = st[X * (S * S + 1) + Y * S + Z];
            float fx = (float)f.x, fy = (float)f.y, fz = (float)f.z;
            float oxv, oyv, ozv;
            sample_v2<S>(st, (float)X, (float)Y, (float)Z, fx, fy, fz,
                         ti.clox, ti.cloy, ti.cloz, ti.chix, ti.chiy, ti.chiz,
                         ti.ihix, ti.ihiy, oxv, oyv, ozv);
            rx[it] = fx + oxv; ry[it] = fy + oyv; rz[it] = fz + ozv;
        }
    }
    __syncthreads();

#pragma unroll
    for (int it = 0; it < 12; ++it) {
        int p = t + it * 512;
        if (p < NI) {
            int si = p / 324;
            int r2 = p - si * 324;
            int sj = r2 / 18;
            int sk = r2 - sj * 18;
            h16x4 o;
            o.x = (h16)rx[it]; o.y = (h16)ry[it]; o.z = (h16)rz[it];
            o.w = (h16)0.0f;
            st[(si + 1) * (S * S + 1) + (sj + 1) * S + (sk + 1)] = o;
        }
    }
    __syncthreads();

    int lz = t & 15, ly = (t >> 4) & 15, lx8 = t >> 8;
#pragma unroll
    for (int i = 0; i < 8; ++i) {
        int lx = lx8 * 8 + i;
        int X = lx + H, Y = ly + H, Z = lz + H;
        h16x4 f = st[X * (S * S + 1) + Y * S + Z];
        float fx = (float)f.x, fy = (float)f.y, fz = (float)f.z;
        float oxv, oyv, ozv;
        sample_v2<S>(st, (float)X, (float)Y, (float)Z, fx, fy, fz,
                     ti.clox, ti.cloy, ti.cloz, ti.chix, ti.chiy, ti.chiz,
                     ti.ihix, ti.ihiy, oxv, oyv, ozv);
        h16x4 o;
        o.x = (h16)(fx + oxv); o.y = (h16)(fy + oyv); o.z = (h16)(fz + ozv);
        o.w = (h16)0.0f;
        ob[((ti.ox + lx) << 14) + ((ti.oy + ly) << 7) + (ti.oz + lz)] = o;
    }
}

// ---- single-step tiled kernel, halo H (step5: H=1, step6: H=2) ---------
template<int H>
__global__ __launch_bounds__(512) void vecint_tileb(
    const h16x4* __restrict__ vin, h16x4* __restrict__ vout)
{
    constexpr int S = 16 + 2 * H;
    __shared__ h16x4 st[S * (S * S + 1)];

    TileInfo ti = tile_info<H>();
    const h16x4* vb = vin + ((size_t)ti.b << 21);
    h16x4* ob = vout + ((size_t)ti.b << 21);
    int t = threadIdx.x;

    for (int s = t; s < S * S * S; s += 512) {
        int si = s / (S * S);
        int r  = s - si * (S * S);
        int sj = r / S;
        int sk = r - sj * S;
        int gx = min(max(ti.ox - H + si, 0), 127);
        int gy = min(max(ti.oy - H + sj, 0), 127);
        int gz = min(max(ti.oz - H + sk, 0), 127);
        st[si * (S * S + 1) + sj * S + sk] = vb[(gx << 14) + (gy << 7) + gz];
    }
    __syncthreads();

    int lz = t & 15, ly = (t >> 4) & 15, lx8 = t >> 8;
#pragma unroll
    for (int i = 0; i < 8; ++i) {
        int lx = lx8 * 8 + i;
        int X = lx + H, Y = ly + H, Z = lz + H;
        h16x4 f = st[X * (S * S + 1) + Y * S + Z];
        float fx = (float)f.x, fy = (float)f.y, fz = (float)f.z;
        float oxv, oyv, ozv;
        sample_v2<S>(st, (float)X, (float)Y, (float)Z, fx, fy, fz,
                     ti.clox, ti.cloy, ti.cloz, ti.chix, ti.chiy, ti.chiz,
                     ti.ihix, ti.ihiy, oxv, oyv, ozv);
        h16x4 o;
        o.x = (h16)(fx + oxv); o.y = (h16)(fy + oyv); o.z = (h16)(fz + ozv);
        o.w = (h16)0.0f;
        ob[((ti.ox + lx) << 14) + ((ti.oy + ly) << 7) + (ti.oz + lz)] = o;
    }
}

// ---- step 7: fp16x4 -> f32 packed (global; disp<4 too big for LDS) -----
__device__ __forceinline__ void tri_setup_pair(
    int x, int y, int z, float fx, float fy, float fz,
    int* offp, float* wxy, float& wz0, float& wz1)
{
    float lx = fminf(fmaxf((float)x + fx, 0.0f), 127.0f);
    float ly = fminf(fmaxf((float)y + fy, 0.0f), 127.0f);
    float lz = fminf(fmaxf((float)z + fz, 0.0f), 127.0f);

    float flx = floorf(lx), fly = floorf(ly), flz = floorf(lz);
    float wx1 = lx - flx, wy1 = ly - fly;
    wz1 = lz - flz;                      // == 0 exactly when z0 == 127
    float wx0 = 1.0f - wx1, wy0 = 1.0f - wy1;
    wz0 = 1.0f - wz1;

    int x0 = (int)flx, y0 = (int)fly, z0 = (int)flz;
    int x1 = min(x0 + 1, 127);
    int y1 = min(y0 + 1, 127);

    offp[0] = (x0 << 14) + (y0 << 7) + z0;
    offp[1] = (x0 << 14) + (y1 << 7) + z0;
    offp[2] = (x1 << 14) + (y0 << 7) + z0;
    offp[3] = (x1 << 14) + (y1 << 7) + z0;
    wxy[0] = wx0 * wy0;  wxy[1] = wx0 * wy1;
    wxy[2] = wx1 * wy0;  wxy[3] = wx1 * wy1;
}

__device__ __forceinline__ void sample_pairs(
    const h16x4* __restrict__ vb, const int* offp, const float* wxy,
    float wz0, float wz1, float& ox, float& oy, float& oz)
{
    f32x4 q0 = *(const f32x4*)(vb + offp[0]);
    f32x4 q1 = *(const f32x4*)(vb + offp[1]);
    f32x4 q2 = *(const f32x4*)(vb + offp[2]);
    f32x4 q3 = *(const f32x4*)(vb + offp[3]);

    h16x8 c0 = __builtin_bit_cast(h16x8, q0);
    h16x8 c1 = __builtin_bit_cast(h16x8, q1);
    h16x8 c2 = __builtin_bit_cast(h16x8, q2);
    h16x8 c3 = __builtin_bit_cast(h16x8, q3);

    float sx0 = wz0 * (float)c0[0] + wz1 * (float)c0[4];
    float sy0 = wz0 * (float)c0[1] + wz1 * (float)c0[5];
    float sz0 = wz0 * (float)c0[2] + wz1 * (float)c0[6];
    float sx1 = wz0 * (float)c1[0] + wz1 * (float)c1[4];
    float sy1 = wz0 * (float)c1[1] + wz1 * (float)c1[5];
    float sz1 = wz0 * (float)c1[2] + wz1 * (float)c1[6];
    float sx2 = wz0 * (float)c2[0] + wz1 * (float)c2[4];
    float sy2 = wz0 * (float)c2[1] + wz1 * (float)c2[5];
    float sz2 = wz0 * (float)c2[2] + wz1 * (float)c2[6];
    float sx3 = wz0 * (float)c3[0] + wz1 * (float)c3[4];
    float sy3 = wz0 * (float)c3[1] + wz1 * (float)c3[5];
    float sz3 = wz0 * (float)c3[2] + wz1 * (float)c3[6];

    ox = wxy[0] * sx0 + wxy[1] * sx1 + wxy[2] * sx2 + wxy[3] * sx3;
    oy = wxy[0] * sy0 + wxy[1] * sy1 + wxy[2] * sy2 + wxy[3] * sy3;
    oz = wxy[0] * sz0 + wxy[1] * sz1 + wxy[2] * sz2 + wxy[3] * sz3;
}

__global__ __launch_bounds__(256, 6) void vecint_last(
    const h16x4* __restrict__ vin, float* __restrict__ vout, int nvox)
{
    int idx = swz_idx();
    if (idx >= nvox) return;

    int z = idx & 127;
    int y = (idx >> 7) & 127;
    int x = (idx >> 14) & 127;
    int b = idx >> 21;

    h16x4 f = vin[idx];
    float fx = (float)f.x, fy = (float)f.y, fz = (float)f.z;

    int offp[4]; float wxy[4], wz0, wz1;
    tri_setup_pair(x, y, z, fx, fy, fz, offp, wxy, wz0, wz1);

    const h16x4* vb = vin + ((size_t)b << 21);
    float ox, oy, oz;
    sample_pairs(vb, offp, wxy, wz0, wz1, ox, oy, oz);

    int base = idx * 3;
    vout[base + 0] = fx + ox;
    vout[base + 1] = fy + oy;
    vout[base + 2] = fz + oz;
}

extern "C" void kernel_launch(void* const* d_in, const int* in_sizes, int n_in,
                              void* d_out, int out_size, void* d_ws, size_t ws_size,
                              hipStream_t stream) {
    const float* vel = (const float*)d_in[0];
    float* out = (float*)d_out;

    int nvox = in_sizes[0] / 3;            // 4,194,304 voxels (2 batches)
    int blocks = (nvox + 255) / 256;       // 16384 (%8==0)
    int tblocks = 1024;                    // 8x8x8 tiles x 2 batches (%8==0)
    float s0 = 1.0f / 128.0f;              // 1 / 2^INT_STEPS

    h16x4* D = (h16x4*)d_out;              // fp16 field in d_out
    h16x4* W = (h16x4*)d_ws;               // fp16 field in d_ws

    // zero 16B past each field: last's global z-pair load hi half (weight 0)
    hipMemsetAsync((char*)d_out + (size_t)nvox * 8, 0, 16, stream);
    hipMemsetAsync((char*)d_ws  + (size_t)nvox * 8, 0, 16, stream);

    vecint_first2  <<<tblocks, 512, 0, stream>>>(vel, D, s0);     // steps 1,2
    vecint_fuse2b  <<<tblocks, 512, 0, stream>>>(D, W);           // steps 3,4
    vecint_tileb<1><<<tblocks, 512, 0, stream>>>(W, D);           // step 5
    vecint_tileb<2><<<tblocks, 512, 0, stream>>>(D, W);           // step 6
    vecint_last    <<<blocks,  256, 0, stream>>>(W, out, nvox);   // step 7
}